// Round 6
// baseline (926.283 us; speedup 1.0000x reference)
//
#include <hip/hip_runtime.h>
#include <stdint.h>

typedef uint16_t u16;
typedef __attribute__((ext_vector_type(8))) __bf16 bfrag8;
typedef __attribute__((ext_vector_type(4))) float f32x4;

#define DEV __device__ __forceinline__

DEV float bf2f(uint32_t lo16) { return __uint_as_float(lo16 << 16); }
DEV u16 f2bf(float f) {
  uint32_t u = __float_as_uint(f);
  u += 0x7fffu + ((u >> 16) & 1u);   // RNE
  return (u16)(u >> 16);
}
DEV uint32_t pack2(float a, float b) { return (uint32_t)f2bf(a) | ((uint32_t)f2bf(b) << 16); }
DEV float sigmoidf_(float x) { return 1.f / (1.f + __expf(-x)); }

// async global->LDS 16B copy (m97 pattern): LDS dest must be wave-uniform base + lane*16
DEV void g2lds16(const u16* g, u16* l) {
  __builtin_amdgcn_global_load_lds(
      (const __attribute__((address_space(1))) void*)g,
      (__attribute__((address_space(3))) void*)l, 16, 0, 0);
}

// block-wide (256-thread) sum; caller must call uniformly
DEV float blk_sum(float v, float* sred, int tid) {
#pragma unroll
  for (int m = 32; m >= 1; m >>= 1) v += __shfl_xor(v, m);
  __syncthreads();
  if ((tid & 63) == 0) sred[tid >> 6] = v;
  __syncthreads();
  return sred[0] + sred[1] + sred[2] + sred[3];
}

// -------------------- weight transpose fp32[K,N] -> bf16[N,K] --------------------
__global__ __launch_bounds__(256) void transpose_w(const float* __restrict__ W,
                                                   u16* __restrict__ WT, int Kd_, int Nd_) {
  __shared__ float tile[32][33];
  int tx = threadIdx.x, ty = threadIdx.y;
  int n0 = blockIdx.x * 32, k0 = blockIdx.y * 32;
#pragma unroll
  for (int i = ty; i < 32; i += 8) tile[i][tx] = W[(size_t)(k0 + i) * Nd_ + n0 + tx];
  __syncthreads();
#pragma unroll
  for (int i = ty; i < 32; i += 8) WT[(size_t)(n0 + i) * Kd_ + k0 + tx] = f2bf(tile[tx][i]);
}

// -------------------- LN1 + RMSnorm + (h@Wa, h@Wb -> {g, beta}) --------------------
__global__ __launch_bounds__(256) void k1_kernel(
    const float* __restrict__ x, const float* __restrict__ ln1g, const float* __restrict__ ln1b,
    const float* __restrict__ rmsw, const float* __restrict__ Wa, const float* __restrict__ Wb,
    const float* __restrict__ dtb, const float* __restrict__ Alog,
    u16* __restrict__ hbf, float2* __restrict__ gb2) {
  __shared__ float sred[4];
  int row = blockIdx.x, tid = threadIdx.x;
  const float4 xv = ((const float4*)(x + (size_t)row * 1024))[tid];
  float ts  = blk_sum(xv.x + xv.y + xv.z + xv.w, sred, tid);
  float ts2 = blk_sum(xv.x * xv.x + xv.y * xv.y + xv.z * xv.z + xv.w * xv.w, sred, tid);
  float mean = ts * (1.f / 1024.f);
  float var  = ts2 * (1.f / 1024.f) - mean * mean;
  float inv  = rsqrtf(var + 1e-5f);
  int c = tid * 4;
  float l0 = (xv.x - mean) * inv * ln1g[c + 0] + ln1b[c + 0];
  float l1 = (xv.y - mean) * inv * ln1g[c + 1] + ln1b[c + 1];
  float l2 = (xv.z - mean) * inv * ln1g[c + 2] + ln1b[c + 2];
  float l3 = (xv.w - mean) * inv * ln1g[c + 3] + ln1b[c + 3];
  float ssq = blk_sum(l0 * l0 + l1 * l1 + l2 * l2 + l3 * l3, sred, tid);
  float rinv = rsqrtf(ssq * (1.f / 1024.f) + 1e-6f);
  float h0 = l0 * rinv * rmsw[c + 0];
  float h1 = l1 * rinv * rmsw[c + 1];
  float h2 = l2 * rinv * rmsw[c + 2];
  float h3 = l3 * rinv * rmsw[c + 3];
  uint2 pk;
  pk.x = pack2(h0, h1);
  pk.y = pack2(h2, h3);
  *(uint2*)(hbf + (size_t)row * 1024 + c) = pk;
  float hv[4] = {h0, h1, h2, h3};
  float pa[4] = {0, 0, 0, 0}, pb[4] = {0, 0, 0, 0};
#pragma unroll
  for (int e = 0; e < 4; e++) {
    const float* wa = Wa + (size_t)(c + e) * 4;
    const float* wb = Wb + (size_t)(c + e) * 4;
#pragma unroll
    for (int p = 0; p < 4; p++) {
      pa[p] = fmaf(hv[e], wa[p], pa[p]);
      pb[p] = fmaf(hv[e], wb[p], pb[p]);
    }
  }
  float ra[4], rb[4];
  for (int p = 0; p < 4; p++) ra[p] = blk_sum(pa[p], sred, tid);
  for (int p = 0; p < 4; p++) rb[p] = blk_sum(pb[p], sred, tid);
  if (tid < 4) {
    float z = ra[tid] + dtb[tid];
    float sp = fmaxf(z, 0.f) + log1pf(expf(-fabsf(z)));   // stable softplus
    float2 o2;
    o2.x = -expf(Alog[tid]) * sp;          // log-decay g
    o2.y = 1.f / (1.f + expf(-rb[tid]));   // beta
    gb2[(size_t)row * 4 + tid] = o2;
  }
}

// -------------------- bf16 MFMA GEMM: C[M,N] = A[M,K] * Bt[N,K]^T --------------------
template <int MODE>
__global__ __launch_bounds__(256) void gemm_bt(
    const u16* __restrict__ A, const u16* __restrict__ Bt, int M, int N, int K,
    float* __restrict__ outf, u16* __restrict__ outh,
    const float* __restrict__ res, const float* __restrict__ bias) {
  __shared__ u16 As[128 * 64];
  __shared__ u16 Bs[128 * 64];
  const int tid = threadIdx.x;
  const int lane = tid & 63;
  const int wv = tid >> 6;
  const int quad = lane >> 4;
  const int l16 = lane & 15;
  const int waveM = (wv & 1) * 64;
  const int waveN = (wv >> 1) * 64;
  const size_t arow0 = (size_t)blockIdx.y * 128;
  const size_t brow0 = (size_t)blockIdx.x * 128;
  const int srow = tid >> 3;
  const int soff = (tid & 7) * 8;
  f32x4 acc[4][4];
#pragma unroll
  for (int i = 0; i < 4; i++)
#pragma unroll
    for (int j = 0; j < 4; j++) acc[i][j] = (f32x4){0.f, 0.f, 0.f, 0.f};

  for (int k0 = 0; k0 < K; k0 += 64) {
    __syncthreads();
#pragma unroll
    for (int i = 0; i < 4; i++) {
      int r = i * 32 + srow;
      g2lds16(A + (arow0 + r) * K + k0 + soff, As + r * 64 + soff);
      g2lds16(Bt + (brow0 + r) * K + k0 + soff, Bs + r * 64 + soff);
    }
    __syncthreads();
#pragma unroll
    for (int kk = 0; kk < 2; kk++) {
      bfrag8 af[4], bfr[4];
#pragma unroll
      for (int i = 0; i < 4; i++) {
        af[i]  = *(const bfrag8*)(As + (waveM + i * 16 + l16) * 64 + kk * 32 + quad * 8);
        bfr[i] = *(const bfrag8*)(Bs + (waveN + i * 16 + l16) * 64 + kk * 32 + quad * 8);
      }
#pragma unroll
      for (int i = 0; i < 4; i++)
#pragma unroll
        for (int j = 0; j < 4; j++)
          acc[i][j] = __builtin_amdgcn_mfma_f32_16x16x32_bf16(af[i], bfr[j], acc[i][j], 0, 0, 0);
    }
  }
#pragma unroll
  for (int i = 0; i < 4; i++) {
    int r0 = (int)arow0 + waveM + i * 16 + quad * 4;
#pragma unroll
    for (int j = 0; j < 4; j++) {
      int cN = (int)brow0 + waveN + j * 16 + l16;
#pragma unroll
      for (int r = 0; r < 4; r++) {
        size_t idx = (size_t)(r0 + r) * N + cN;
        float vacc = acc[i][j][r];
        if (MODE == 0) {
          outh[idx] = f2bf(vacc);
        } else if (MODE == 1) {
          outf[idx] = vacc + res[idx];
        } else {
          float z = vacc + bias[cN];
          float ge = 0.5f * z * (1.f + erff(z * 0.70710678118654752f));
          outf[idx] = ge + res[idx];
        }
      }
    }
  }
}

// -------------------- causal conv(4) + SiLU + L2norm for q,k (bf16 out) --------------------
__global__ __launch_bounds__(256) void conv_qk_kernel(
    const u16* __restrict__ qkv, const float* __restrict__ cwq, const float* __restrict__ cwk,
    u16* __restrict__ qf, u16* __restrict__ kf) {
  __shared__ float sred[4];
  int row = blockIdx.x, tid = threadIdx.x;
  int t = row & 2047;
  int isK = (blockIdx.y >= 4);
  int hh = blockIdx.y & 3;
  int c = hh * 256 + tid;
  const float* cw = isK ? cwk : cwq;
  int col = (isK ? 1024 : 0) + c;
  float acc = 0.f;
#pragma unroll
  for (int i = 0; i < 4; i++) {
    int tt = t - 3 + i;
    if (tt >= 0) acc = fmaf(cw[c * 4 + i], bf2f(qkv[(size_t)(row - 3 + i) * 4096 + col]), acc);
  }
  float y = acc * sigmoidf_(acc);
  float ssq = blk_sum(y * y, sred, tid);
  float r = rsqrtf(ssq + 1e-6f);
  float outv = y * r * (isK ? 1.f : 0.0625f);
  (isK ? kf : qf)[(size_t)row * 1024 + c] = f2bf(outv);
}

// -------------------- causal conv(4) + SiLU for v (bf16 out) --------------------
__global__ __launch_bounds__(256) void conv_v_kernel(
    const u16* __restrict__ qkv, const float* __restrict__ cwv, u16* __restrict__ vf) {
  int row = blockIdx.x, tid = threadIdx.x;
  int t = row & 2047;
  int c0 = blockIdx.y * 1024 + tid * 4;
  float a0 = 0, a1 = 0, a2 = 0, a3 = 0;
#pragma unroll
  for (int i = 0; i < 4; i++) {
    int tt = t - 3 + i;
    if (tt >= 0) {
      uint2 raw = *(const uint2*)(qkv + (size_t)(row - 3 + i) * 4096 + 2048 + c0);
      a0 = fmaf(cwv[(c0 + 0) * 4 + i], bf2f(raw.x & 0xffffu), a0);
      a1 = fmaf(cwv[(c0 + 1) * 4 + i], bf2f(raw.x >> 16), a1);
      a2 = fmaf(cwv[(c0 + 2) * 4 + i], bf2f(raw.y & 0xffffu), a2);
      a3 = fmaf(cwv[(c0 + 3) * 4 + i], bf2f(raw.y >> 16), a3);
    }
  }
  a0 = a0 * sigmoidf_(a0);
  a1 = a1 * sigmoidf_(a1);
  a2 = a2 * sigmoidf_(a2);
  a3 = a3 * sigmoidf_(a3);
  uint2 pk;
  pk.x = pack2(a0, a1);
  pk.y = pack2(a2, a3);
  *(uint2*)(vf + (size_t)row * 2048 + c0) = pk;
}

// ==================== chunked gated delta rule ====================
// Chunk C=64. Per chunk, with G_i = cumsum(g) (inclusive), gamma_i = exp(G_i):
//   A_ij = exp(G_i-G_j) k_i.k_j (j<i);  M = (I + diag(b) A)^-1 diag(b)
//   delta = M (V - rowscale(gamma) K S0);  O_i = gamma_i (Q S0)_i + (B delta)_i,
//   B_ij = exp(G_i-G_j) q_i.k_j (j<=i);   S' = gamma_63 S0 + K^T rowscale(exp(G63-G_i)) delta

// -------- Phase A: per (b,h,chunk) block: emits M, B (bf16), KT (bf16), gamma pack --------
__global__ __launch_bounds__(256) void phaseA_kernel(
    const u16* __restrict__ kf, const u16* __restrict__ qf, const float2* __restrict__ gb2,
    u16* __restrict__ KTg, u16* __restrict__ Bg, u16* __restrict__ Mg,
    float2* __restrict__ gpk) {
  __shared__ uint8_t sm[51456];
  float* Nl  = (float*)sm;               // 64*66*4 = 16896
  float* gl  = (float*)(sm + 16896);     // 256
  float* bl  = (float*)(sm + 17152);     // 256
  float* GL  = (float*)(sm + 17408);     // 256
  u16*  Klds = (u16*)(sm + 17664);       // 64*264*2 = 33792
  float* Ml  = (float*)(sm + 17664);     // alias Klds (used after KT writeout)

  const int tid = threadIdx.x;
  const int lane = tid & 63;
  const int wv = tid >> 6;
  const int quad = lane >> 4;
  const int l16 = lane & 15;
  const int bh = blockIdx.x >> 5;        // 0..15
  const int ch = blockIdx.x & 31;        // 0..31
  const int b = bh >> 2, h = bh & 3;
  const int gr0 = b * 2048 + ch * 64;
  const size_t cid2 = (size_t)bh * 32 + ch;

  if (tid < 64) {
    float2 gv = gb2[(size_t)(gr0 + tid) * 4 + h];
    gl[tid] = gv.x; bl[tid] = gv.y;
  }
  __syncthreads();
  if (tid < 64) {
    float s = 0.f;
    for (int j = 0; j < 64; j++) { if (j <= tid) s += gl[j]; }
    GL[tid] = s;
  }
  {
    int r = tid >> 2, p = tid & 3;
    const u16* src = kf + (size_t)(gr0 + r) * 1024 + h * 256 + p * 64;
#pragma unroll
    for (int it = 0; it < 8; it++)
      *(uint4*)&Klds[r * 264 + p * 64 + it * 8] = *(const uint4*)(src + it * 8);
  }
  f32x4 ap[4], aq4[4];
#pragma unroll
  for (int nt = 0; nt < 4; nt++) { ap[nt] = (f32x4){0, 0, 0, 0}; aq4[nt] = (f32x4){0, 0, 0, 0}; }
  for (int ks = 0; ks < 8; ks++) {
    bfrag8 afk = *(const bfrag8*)(kf + (size_t)(gr0 + 16 * wv + l16) * 1024 + h * 256 + ks * 32 + quad * 8);
    bfrag8 afq = *(const bfrag8*)(qf + (size_t)(gr0 + 16 * wv + l16) * 1024 + h * 256 + ks * 32 + quad * 8);
#pragma unroll
    for (int nt = 0; nt < 4; nt++) {
      bfrag8 bfk = *(const bfrag8*)(kf + (size_t)(gr0 + 16 * nt + l16) * 1024 + h * 256 + ks * 32 + quad * 8);
      ap[nt]  = __builtin_amdgcn_mfma_f32_16x16x32_bf16(afk, bfk, ap[nt], 0, 0, 0);
      aq4[nt] = __builtin_amdgcn_mfma_f32_16x16x32_bf16(afq, bfk, aq4[nt], 0, 0, 0);
    }
  }
  __syncthreads();   // GL ready, Klds staged
#pragma unroll
  for (int nt = 0; nt < 4; nt++) {
#pragma unroll
    for (int r = 0; r < 4; r++) {
      int i = 16 * wv + quad * 4 + r;
      int j = 16 * nt + l16;
      float e = __expf(GL[i] - GL[j]);
      Nl[i * 66 + j] = (j < i) ? bl[i] * e * ap[nt][r] : 0.f;
      float bvv = (j <= i) ? e * aq4[nt][r] : 0.f;
      Bg[cid2 * 4096 + i * 64 + j] = f2bf(bvv);
    }
  }
  for (int e = 0; e < 64; e++) {
    int idx = e * 256 + tid;
    int i2 = idx & 63, k2 = idx >> 6;
    KTg[cid2 * 16384 + (size_t)k2 * 64 + i2] = Klds[i2 * 264 + k2];
  }
  if (tid < 64) {
    float2 gp;
    gp.x = __expf(GL[tid]);
    gp.y = __expf(GL[63] - GL[tid]);
    gpk[cid2 * 64 + tid] = gp;
  }
  __syncthreads();   // N complete; KT writeout done (Ml aliases Klds)
  if (tid < 64) {
    int c = tid;
    for (int i = 0; i < 64; i++) {
      float acc = (i == c) ? bl[i] : 0.f;
      for (int j = 0; j < i; j++) acc -= Nl[i * 66 + j] * Ml[j * 66 + c];
      Ml[i * 66 + c] = acc;
    }
  }
  __syncthreads();
  for (int e = 0; e < 16; e++) {
    int idx = e * 256 + tid;
    int i2 = idx >> 6, j2 = idx & 63;
    Mg[cid2 * 4096 + i2 * 64 + j2] = f2bf(Ml[i2 * 66 + j2]);
  }
}

// -------- Phase B: per (b,h,v-slice16) block; sequential over 32 chunks --------
// 512 blocks (2 per CU) for latency overlap; each wave owns 64 k-dims x 16 v-cols.
__global__ __launch_bounds__(256) void phaseB_kernel(
    const u16* __restrict__ kf, const u16* __restrict__ qf, const u16* __restrict__ vf,
    const u16* __restrict__ KTg, const u16* __restrict__ Bg, const u16* __restrict__ Mg,
    const float2* __restrict__ gpk, u16* __restrict__ obuf) {
  __shared__ u16 S0T[16 * 264];   // S0^T [n][k], padded
  __shared__ u16 rhsT[16 * 72];
  __shared__ u16 dT[16 * 72];
  __shared__ u16 dhT[16 * 72];
  __shared__ float gin_s[64], gout_s[64];

  const int tid = threadIdx.x;
  const int lane = tid & 63;
  const int wv = tid >> 6;
  const int quad = lane >> 4;
  const int l16 = lane & 15;
  const int bh = blockIdx.x >> 5;   // 0..15
  const int sl = blockIdx.x & 31;   // v-slice of 16
  const int b = bh >> 2, h = bh & 3;

  f32x4 S[4];                       // k-tile(4); wave wv owns k in [64*wv, 64*wv+64)
#pragma unroll
  for (int t = 0; t < 4; t++) S[t] = (f32x4){0, 0, 0, 0};

  for (int ch = 0; ch < 32; ch++) {
    const size_t cid = (size_t)bh * 32 + ch;
    const int gr0 = b * 2048 + ch * 64;
    const u16* kfc = kf + (size_t)gr0 * 1024 + h * 256;
    const u16* qfc = qf + (size_t)gr0 * 1024 + h * 256;
    const u16* vfc = vf + (size_t)gr0 * 2048 + h * 512 + sl * 16;
    u16* oc = obuf + (size_t)gr0 * 2048 + h * 512 + sl * 16;
    const u16* KTc = KTg + cid * 16384;
    const u16* Mc  = Mg + cid * 4096;
    const u16* Bc  = Bg + cid * 4096;

    // step 1: stage gammas + S0^T (bf16)
    if (tid < 64) {
      float2 gp = gpk[cid * 64 + tid];
      gin_s[tid] = gp.x; gout_s[tid] = gp.y;
    }
#pragma unroll
    for (int kt = 0; kt < 4; kt++) {
      int k = wv * 64 + kt * 16 + quad * 4;
      f32x4 sv = S[kt];
      uint2 pk;
      pk.x = pack2(sv[0], sv[1]);
      pk.y = pack2(sv[2], sv[3]);
      *(uint2*)&S0T[l16 * 264 + k] = pk;
    }
    __syncthreads();

    // step 2: rhs = V - rowscale(gin) * (K @ S0)
    f32x4 ar = (f32x4){0, 0, 0, 0};
    for (int ks = 0; ks < 8; ks++) {
      bfrag8 af = *(const bfrag8*)(kfc + (size_t)(16 * wv + l16) * 1024 + ks * 32 + quad * 8);
      bfrag8 bf = *(const bfrag8*)&S0T[l16 * 264 + ks * 32 + quad * 8];
      ar = __builtin_amdgcn_mfma_f32_16x16x32_bf16(af, bf, ar, 0, 0, 0);
    }
    {
      float rv[4];
#pragma unroll
      for (int r = 0; r < 4; r++) {
        int i = 16 * wv + quad * 4 + r;
        float vvv = bf2f(vfc[(size_t)i * 2048 + l16]);
        rv[r] = vvv - gin_s[i] * ar[r];
      }
      uint2 pk;
      pk.x = pack2(rv[0], rv[1]);
      pk.y = pack2(rv[2], rv[3]);
      *(uint2*)&rhsT[l16 * 72 + 16 * wv + quad * 4] = pk;
    }
    __syncthreads();

    // step 3: delta = M @ rhs; write dT (raw) and dhT (rowscale gout)
    f32x4 ad = (f32x4){0, 0, 0, 0};
    for (int ks = 0; ks < 2; ks++) {
      bfrag8 af = *(const bfrag8*)(Mc + (size_t)(16 * wv + l16) * 64 + ks * 32 + quad * 8);
      bfrag8 bf = *(const bfrag8*)&rhsT[l16 * 72 + ks * 32 + quad * 8];
      ad = __builtin_amdgcn_mfma_f32_16x16x32_bf16(af, bf, ad, 0, 0, 0);
    }
    {
      int i0 = 16 * wv + quad * 4;
      uint2 pk;
      pk.x = pack2(ad[0], ad[1]);
      pk.y = pack2(ad[2], ad[3]);
      *(uint2*)&dT[l16 * 72 + i0] = pk;
      uint2 pk2;
      pk2.x = pack2(gout_s[i0] * ad[0], gout_s[i0 + 1] * ad[1]);
      pk2.y = pack2(gout_s[i0 + 2] * ad[2], gout_s[i0 + 3] * ad[3]);
      *(uint2*)&dhT[l16 * 72 + i0] = pk2;
    }
    __syncthreads();

    // step 4: O = rowscale(gin) * (Q @ S0) + B @ delta
    f32x4 ao = (f32x4){0, 0, 0, 0};
    for (int ks = 0; ks < 2; ks++) {
      bfrag8 af = *(const bfrag8*)(Bc + (size_t)(16 * wv + l16) * 64 + ks * 32 + quad * 8);
      bfrag8 bf = *(const bfrag8*)&dT[l16 * 72 + ks * 32 + quad * 8];
      ao = __builtin_amdgcn_mfma_f32_16x16x32_bf16(af, bf, ao, 0, 0, 0);
    }
    f32x4 aq = (f32x4){0, 0, 0, 0};
    for (int ks = 0; ks < 8; ks++) {
      bfrag8 af = *(const bfrag8*)(qfc + (size_t)(16 * wv + l16) * 1024 + ks * 32 + quad * 8);
      bfrag8 bf = *(const bfrag8*)&S0T[l16 * 264 + ks * 32 + quad * 8];
      aq = __builtin_amdgcn_mfma_f32_16x16x32_bf16(af, bf, aq, 0, 0, 0);
    }
#pragma unroll
    for (int r = 0; r < 4; r++) {
      int i = 16 * wv + quad * 4 + r;
      float ov = gin_s[i] * aq[r] + ao[r];
      oc[(size_t)i * 2048 + l16] = f2bf(ov);
    }

    // step 5: S = gammaC * S + KT @ dhat
    float gC = gin_s[63];
#pragma unroll
    for (int kt = 0; kt < 4; kt++) {
      f32x4 c0 = S[kt] * gC;
      for (int ks = 0; ks < 2; ks++) {
        bfrag8 af = *(const bfrag8*)(KTc + (size_t)(wv * 64 + kt * 16 + l16) * 64 + ks * 32 + quad * 8);
        bfrag8 bf = *(const bfrag8*)&dhT[l16 * 72 + ks * 32 + quad * 8];
        c0 = __builtin_amdgcn_mfma_f32_16x16x32_bf16(af, bf, c0, 0, 0, 0);
      }
      S[kt] = c0;
    }
    __syncthreads();   // protect S0T/rhsT/dT for next chunk
  }
}

// -------------------- gated RMS-norm of o: bf16 out --------------------
__global__ __launch_bounds__(256) void onorm_kernel(
    const u16* __restrict__ o, const u16* __restrict__ gate,
    const float* __restrict__ onw, u16* __restrict__ ofin) {
  __shared__ float sred[4];
  int row = blockIdx.x, hh = blockIdx.y, tid = threadIdx.x;
  size_t base = (size_t)row * 2048 + hh * 512;
  uint32_t oraw = *(const uint32_t*)(o + base + tid * 2);
  float o0 = bf2f(oraw & 0xffffu), o1 = bf2f(oraw >> 16);
  float ssq = blk_sum(o0 * o0 + o1 * o1, sred, tid);
  float rinv = rsqrtf(ssq * (1.f / 512.f) + 1e-6f);
  uint32_t graw = *(const uint32_t*)(gate + base + tid * 2);
  float g0 = bf2f(graw & 0xffffu), g1 = bf2f(graw >> 16);
  float r0 = o0 * rinv * onw[tid * 2 + 0] * (g0 * sigmoidf_(g0));
  float r1 = o1 * rinv * onw[tid * 2 + 1] * (g1 * sigmoidf_(g1));
  *(uint32_t*)(ofin + base + tid * 2) = pack2(r0, r1);
}

// -------------------- LN2 --------------------
__global__ __launch_bounds__(256) void ln2_kernel(
    const float* __restrict__ x1, const float* __restrict__ g2, const float* __restrict__ b2,
    u16* __restrict__ h2) {
  __shared__ float sred[4];
  int row = blockIdx.x, tid = threadIdx.x;
  const float4 xv = ((const float4*)(x1 + (size_t)row * 1024))[tid];
  float ts  = blk_sum(xv.x + xv.y + xv.z + xv.w, sred, tid);
  float ts2 = blk_sum(xv.x * xv.x + xv.y * xv.y + xv.z * xv.z + xv.w * xv.w, sred, tid);
  float mean = ts * (1.f / 1024.f);
  float inv = rsqrtf(ts2 * (1.f / 1024.f) - mean * mean + 1e-5f);
  int c = tid * 4;
  float h0 = (xv.x - mean) * inv * g2[c + 0] + b2[c + 0];
  float h1 = (xv.y - mean) * inv * g2[c + 1] + b2[c + 1];
  float h2v = (xv.z - mean) * inv * g2[c + 2] + b2[c + 2];
  float h3 = (xv.w - mean) * inv * g2[c + 3] + b2[c + 3];
  uint2 pk;
  pk.x = pack2(h0, h1);
  pk.y = pack2(h2v, h3);
  *(uint2*)(h2 + (size_t)row * 1024 + c) = pk;
}

// ==================== launch ====================
extern "C" void kernel_launch(void* const* d_in, const int* in_sizes, int n_in,
                              void* d_out, int out_size, void* d_ws, size_t ws_size,
                              hipStream_t stream) {
  (void)in_sizes; (void)n_in; (void)out_size; (void)ws_size;
  const float* x    = (const float*)d_in[0];
  const float* ln1g = (const float*)d_in[1];
  const float* ln1b = (const float*)d_in[2];
  const float* ln2g = (const float*)d_in[3];
  const float* ln2b = (const float*)d_in[4];
  const float* rmsw = (const float*)d_in[5];
  const float* Wq   = (const float*)d_in[6];
  const float* Wk   = (const float*)d_in[7];
  const float* Wv   = (const float*)d_in[8];
  const float* cwq  = (const float*)d_in[9];
  const float* cwk  = (const float*)d_in[10];
  const float* cwv  = (const float*)d_in[11];
  const float* Wa   = (const float*)d_in[12];
  const float* dtb  = (const float*)d_in[13];
  const float* Alog = (const float*)d_in[14];
  const float* Wb   = (const float*)d_in[15];
  const float* Wg   = (const float*)d_in[16];
  const float* onw  = (const float*)d_in[17];
  const float* Wo   = (const float*)d_in[18];
  const float* W2   = (const float*)d_in[19];
  const float* b2   = (const float*)d_in[20];

  uint8_t* ws = (uint8_t*)d_ws;
  const size_t MB = 1024ull * 1024;
  u16*   qkvp  = (u16*)(ws);               // 64MB
  u16*   obuf  = (u16*)(ws);               // 32MB (overlay)
  u16*   KTg   = (u16*)(ws + 32 * MB);     // 16MB  (PhaseA out, dead before gate write)
  u16*   Bg    = (u16*)(ws + 48 * MB);     // 4MB
  u16*   Mg    = (u16*)(ws + 52 * MB);     // 4MB
  float2* gpk  = (float2*)(ws + 56 * MB);  // 256KB
  u16*   gate  = (u16*)(ws + 32 * MB);     // 32MB (overlay, written after PhaseB)
  u16*   hbf   = (u16*)(ws + 64 * MB);     // 16MB
  u16*   WTqkv = (u16*)(ws + 80 * MB);     // 8MB
  u16*   WgT   = (u16*)(ws + 88 * MB);     // 4MB
  u16*   WoT   = (u16*)(ws + 92 * MB);     // 4MB
  u16*   W2T   = (u16*)(ws + 96 * MB);     // 2MB
  u16*   qf    = (u16*)(ws + 98 * MB);     // 16MB
  u16*   kf    = (u16*)(ws + 114 * MB);    // 16MB
  u16*   vf    = (u16*)(ws + 130 * MB);    // 32MB
  u16*   ofin  = (u16*)(ws + 98 * MB);     // 32MB (overlay qf/kf)
  u16*   h2bf  = (u16*)(ws + 130 * MB);    // 16MB (overlay vf)
  float2* gb2  = (float2*)(ws + 162 * MB); // 256KB
  float* x1    = (float*)d_out;
  float* outp  = (float*)d_out;

  dim3 tb(32, 8);
  transpose_w<<<dim3(32, 32), tb, 0, stream>>>(Wq, WTqkv,               1024, 1024);
  transpose_w<<<dim3(32, 32), tb, 0, stream>>>(Wk, WTqkv + 1024 * 1024, 1024, 1024);
  transpose_w<<<dim3(64, 32), tb, 0, stream>>>(Wv, WTqkv + 2048 * 1024, 1024, 2048);
  transpose_w<<<dim3(64, 32), tb, 0, stream>>>(Wg, WgT,                 1024, 2048);
  transpose_w<<<dim3(32, 64), tb, 0, stream>>>(Wo, WoT,                 2048, 1024);
  transpose_w<<<dim3(32, 32), tb, 0, stream>>>(W2, W2T,                 1024, 1024);

  k1_kernel<<<8192, 256, 0, stream>>>(x, ln1g, ln1b, rmsw, Wa, Wb, dtb, Alog, hbf, gb2);
  gemm_bt<0><<<dim3(32, 64), 256, 0, stream>>>(hbf, WTqkv, 8192, 4096, 1024, nullptr, qkvp, nullptr, nullptr);
  conv_qk_kernel<<<dim3(8192, 8), 256, 0, stream>>>(qkvp, cwq, cwk, qf, kf);
  conv_v_kernel<<<dim3(8192, 2), 256, 0, stream>>>(qkvp, cwv, vf);
  phaseA_kernel<<<512, 256, 0, stream>>>(kf, qf, gb2, KTg, Bg, Mg, gpk);
  phaseB_kernel<<<512, 256, 0, stream>>>(kf, qf, vf, KTg, Bg, Mg, gpk, obuf);
  gemm_bt<0><<<dim3(16, 64), 256, 0, stream>>>(hbf, WgT, 8192, 2048, 1024, nullptr, gate, nullptr, nullptr);
  onorm_kernel<<<dim3(8192, 4), 256, 0, stream>>>(obuf, gate, onw, ofin);
  gemm_bt<1><<<dim3(8, 64), 256, 0, stream>>>(ofin, WoT, 8192, 1024, 2048, x1, nullptr, x, nullptr);
  ln2_kernel<<<8192, 256, 0, stream>>>(x1, ln2g, ln2b, h2bf);
  gemm_bt<2><<<dim3(8, 64), 256, 0, stream>>>(h2bf, W2T, 8192, 1024, 1024, outp, nullptr, x1, b2);
}

// Round 7
// 847.397 us; speedup vs baseline: 1.0931x; 1.0931x over previous
//
#include <hip/hip_runtime.h>
#include <stdint.h>

typedef uint16_t u16;
typedef __attribute__((ext_vector_type(8))) __bf16 bfrag8;
typedef __attribute__((ext_vector_type(4))) float f32x4;

#define DEV __device__ __forceinline__

DEV float bf2f(uint32_t lo16) { return __uint_as_float(lo16 << 16); }
DEV u16 f2bf(float f) {
  uint32_t u = __float_as_uint(f);
  u += 0x7fffu + ((u >> 16) & 1u);   // RNE
  return (u16)(u >> 16);
}
DEV uint32_t pack2(float a, float b) { return (uint32_t)f2bf(a) | ((uint32_t)f2bf(b) << 16); }
DEV float sigmoidf_(float x) { return 1.f / (1.f + __expf(-x)); }

// async global->LDS 16B copy (m97 pattern): LDS dest must be wave-uniform base + lane*16
DEV void g2lds16(const u16* g, u16* l) {
  __builtin_amdgcn_global_load_lds(
      (const __attribute__((address_space(1))) void*)g,
      (__attribute__((address_space(3))) void*)l, 16, 0, 0);
}

// block-wide (256-thread) sum; caller must call uniformly
DEV float blk_sum(float v, float* sred, int tid) {
#pragma unroll
  for (int m = 32; m >= 1; m >>= 1) v += __shfl_xor(v, m);
  __syncthreads();
  if ((tid & 63) == 0) sred[tid >> 6] = v;
  __syncthreads();
  return sred[0] + sred[1] + sred[2] + sred[3];
}

// -------------------- weight transpose fp32[K,N] -> bf16[N,K] --------------------
__global__ __launch_bounds__(256) void transpose_w(const float* __restrict__ W,
                                                   u16* __restrict__ WT, int Kd_, int Nd_) {
  __shared__ float tile[32][33];
  int tx = threadIdx.x, ty = threadIdx.y;
  int n0 = blockIdx.x * 32, k0 = blockIdx.y * 32;
#pragma unroll
  for (int i = ty; i < 32; i += 8) tile[i][tx] = W[(size_t)(k0 + i) * Nd_ + n0 + tx];
  __syncthreads();
#pragma unroll
  for (int i = ty; i < 32; i += 8) WT[(size_t)(n0 + i) * Kd_ + k0 + tx] = f2bf(tile[tx][i]);
}

// -------------------- LN1 + RMSnorm + (h@Wa, h@Wb -> {g, beta}) --------------------
__global__ __launch_bounds__(256) void k1_kernel(
    const float* __restrict__ x, const float* __restrict__ ln1g, const float* __restrict__ ln1b,
    const float* __restrict__ rmsw, const float* __restrict__ Wa, const float* __restrict__ Wb,
    const float* __restrict__ dtb, const float* __restrict__ Alog,
    u16* __restrict__ hbf, float2* __restrict__ gb2) {
  __shared__ float sred[4];
  int row = blockIdx.x, tid = threadIdx.x;
  const float4 xv = ((const float4*)(x + (size_t)row * 1024))[tid];
  float ts  = blk_sum(xv.x + xv.y + xv.z + xv.w, sred, tid);
  float ts2 = blk_sum(xv.x * xv.x + xv.y * xv.y + xv.z * xv.z + xv.w * xv.w, sred, tid);
  float mean = ts * (1.f / 1024.f);
  float var  = ts2 * (1.f / 1024.f) - mean * mean;
  float inv  = rsqrtf(var + 1e-5f);
  int c = tid * 4;
  float l0 = (xv.x - mean) * inv * ln1g[c + 0] + ln1b[c + 0];
  float l1 = (xv.y - mean) * inv * ln1g[c + 1] + ln1b[c + 1];
  float l2 = (xv.z - mean) * inv * ln1g[c + 2] + ln1b[c + 2];
  float l3 = (xv.w - mean) * inv * ln1g[c + 3] + ln1b[c + 3];
  float ssq = blk_sum(l0 * l0 + l1 * l1 + l2 * l2 + l3 * l3, sred, tid);
  float rinv = rsqrtf(ssq * (1.f / 1024.f) + 1e-6f);
  float h0 = l0 * rinv * rmsw[c + 0];
  float h1 = l1 * rinv * rmsw[c + 1];
  float h2 = l2 * rinv * rmsw[c + 2];
  float h3 = l3 * rinv * rmsw[c + 3];
  uint2 pk;
  pk.x = pack2(h0, h1);
  pk.y = pack2(h2, h3);
  *(uint2*)(hbf + (size_t)row * 1024 + c) = pk;
  float hv[4] = {h0, h1, h2, h3};
  float pa[4] = {0, 0, 0, 0}, pb[4] = {0, 0, 0, 0};
#pragma unroll
  for (int e = 0; e < 4; e++) {
    const float* wa = Wa + (size_t)(c + e) * 4;
    const float* wb = Wb + (size_t)(c + e) * 4;
#pragma unroll
    for (int p = 0; p < 4; p++) {
      pa[p] = fmaf(hv[e], wa[p], pa[p]);
      pb[p] = fmaf(hv[e], wb[p], pb[p]);
    }
  }
  float ra[4], rb[4];
  for (int p = 0; p < 4; p++) ra[p] = blk_sum(pa[p], sred, tid);
  for (int p = 0; p < 4; p++) rb[p] = blk_sum(pb[p], sred, tid);
  if (tid < 4) {
    float z = ra[tid] + dtb[tid];
    float sp = fmaxf(z, 0.f) + log1pf(expf(-fabsf(z)));   // stable softplus
    float2 o2;
    o2.x = -expf(Alog[tid]) * sp;          // log-decay g
    o2.y = 1.f / (1.f + expf(-rb[tid]));   // beta
    gb2[(size_t)row * 4 + tid] = o2;
  }
}

// -------------------- bf16 MFMA GEMM: C[M,N] = A[M,K] * Bt[N,K]^T --------------------
template <int MODE>
__global__ __launch_bounds__(256) void gemm_bt(
    const u16* __restrict__ A, const u16* __restrict__ Bt, int M, int N, int K,
    float* __restrict__ outf, u16* __restrict__ outh,
    const float* __restrict__ res, const float* __restrict__ bias) {
  __shared__ u16 As[128 * 64];
  __shared__ u16 Bs[128 * 64];
  const int tid = threadIdx.x;
  const int lane = tid & 63;
  const int wv = tid >> 6;
  const int quad = lane >> 4;
  const int l16 = lane & 15;
  const int waveM = (wv & 1) * 64;
  const int waveN = (wv >> 1) * 64;
  const size_t arow0 = (size_t)blockIdx.y * 128;
  const size_t brow0 = (size_t)blockIdx.x * 128;
  const int srow = tid >> 3;
  const int soff = (tid & 7) * 8;
  f32x4 acc[4][4];
#pragma unroll
  for (int i = 0; i < 4; i++)
#pragma unroll
    for (int j = 0; j < 4; j++) acc[i][j] = (f32x4){0.f, 0.f, 0.f, 0.f};

  for (int k0 = 0; k0 < K; k0 += 64) {
    __syncthreads();
#pragma unroll
    for (int i = 0; i < 4; i++) {
      int r = i * 32 + srow;
      g2lds16(A + (arow0 + r) * K + k0 + soff, As + r * 64 + soff);
      g2lds16(Bt + (brow0 + r) * K + k0 + soff, Bs + r * 64 + soff);
    }
    __syncthreads();
#pragma unroll
    for (int kk = 0; kk < 2; kk++) {
      bfrag8 af[4], bfr[4];
#pragma unroll
      for (int i = 0; i < 4; i++) {
        af[i]  = *(const bfrag8*)(As + (waveM + i * 16 + l16) * 64 + kk * 32 + quad * 8);
        bfr[i] = *(const bfrag8*)(Bs + (waveN + i * 16 + l16) * 64 + kk * 32 + quad * 8);
      }
#pragma unroll
      for (int i = 0; i < 4; i++)
#pragma unroll
        for (int j = 0; j < 4; j++)
          acc[i][j] = __builtin_amdgcn_mfma_f32_16x16x32_bf16(af[i], bfr[j], acc[i][j], 0, 0, 0);
    }
  }
#pragma unroll
  for (int i = 0; i < 4; i++) {
    int r0 = (int)arow0 + waveM + i * 16 + quad * 4;
#pragma unroll
    for (int j = 0; j < 4; j++) {
      int cN = (int)brow0 + waveN + j * 16 + l16;
#pragma unroll
      for (int r = 0; r < 4; r++) {
        size_t idx = (size_t)(r0 + r) * N + cN;
        float vacc = acc[i][j][r];
        if (MODE == 0) {
          outh[idx] = f2bf(vacc);
        } else if (MODE == 1) {
          outf[idx] = vacc + res[idx];
        } else {
          float z = vacc + bias[cN];
          float ge = 0.5f * z * (1.f + erff(z * 0.70710678118654752f));
          outf[idx] = ge + res[idx];
        }
      }
    }
  }
}

// -------------------- causal conv(4) + SiLU + L2norm for q,k (bf16 out) --------------------
__global__ __launch_bounds__(256) void conv_qk_kernel(
    const u16* __restrict__ qkv, const float* __restrict__ cwq, const float* __restrict__ cwk,
    u16* __restrict__ qf, u16* __restrict__ kf) {
  __shared__ float sred[4];
  int row = blockIdx.x, tid = threadIdx.x;
  int t = row & 2047;
  int isK = (blockIdx.y >= 4);
  int hh = blockIdx.y & 3;
  int c = hh * 256 + tid;
  const float* cw = isK ? cwk : cwq;
  int col = (isK ? 1024 : 0) + c;
  float acc = 0.f;
#pragma unroll
  for (int i = 0; i < 4; i++) {
    int tt = t - 3 + i;
    if (tt >= 0) acc = fmaf(cw[c * 4 + i], bf2f(qkv[(size_t)(row - 3 + i) * 4096 + col]), acc);
  }
  float y = acc * sigmoidf_(acc);
  float ssq = blk_sum(y * y, sred, tid);
  float r = rsqrtf(ssq + 1e-6f);
  float outv = y * r * (isK ? 1.f : 0.0625f);
  (isK ? kf : qf)[(size_t)row * 1024 + c] = f2bf(outv);
}

// -------------------- causal conv(4) + SiLU for v (bf16 out) --------------------
__global__ __launch_bounds__(256) void conv_v_kernel(
    const u16* __restrict__ qkv, const float* __restrict__ cwv, u16* __restrict__ vf) {
  int row = blockIdx.x, tid = threadIdx.x;
  int t = row & 2047;
  int c0 = blockIdx.y * 1024 + tid * 4;
  float a0 = 0, a1 = 0, a2 = 0, a3 = 0;
#pragma unroll
  for (int i = 0; i < 4; i++) {
    int tt = t - 3 + i;
    if (tt >= 0) {
      uint2 raw = *(const uint2*)(qkv + (size_t)(row - 3 + i) * 4096 + 2048 + c0);
      a0 = fmaf(cwv[(c0 + 0) * 4 + i], bf2f(raw.x & 0xffffu), a0);
      a1 = fmaf(cwv[(c0 + 1) * 4 + i], bf2f(raw.x >> 16), a1);
      a2 = fmaf(cwv[(c0 + 2) * 4 + i], bf2f(raw.y & 0xffffu), a2);
      a3 = fmaf(cwv[(c0 + 3) * 4 + i], bf2f(raw.y >> 16), a3);
    }
  }
  a0 = a0 * sigmoidf_(a0);
  a1 = a1 * sigmoidf_(a1);
  a2 = a2 * sigmoidf_(a2);
  a3 = a3 * sigmoidf_(a3);
  uint2 pk;
  pk.x = pack2(a0, a1);
  pk.y = pack2(a2, a3);
  *(uint2*)(vf + (size_t)row * 2048 + c0) = pk;
}

// ==================== chunked gated delta rule ====================
// Chunk C=64. Per chunk, with G_i = cumsum(g) (inclusive), gamma_i = exp(G_i):
//   A_ij = exp(G_i-G_j) k_i.k_j (j<i);  M = (I + diag(b) A)^-1 diag(b)
//   delta = M (V - rowscale(gamma) K S0);  O_i = gamma_i (Q S0)_i + (B delta)_i,
//   B_ij = exp(G_i-G_j) q_i.k_j (j<=i);
//   S' = gammaC S0 + KTs @ delta, where KTs[k][i] = K[i][k]*exp(G63-G_i) (pre-scaled in phaseA)

// -------- Phase A: per (b,h,chunk) block: emits M, B, KTs (bf16), gamma pack --------
__global__ __launch_bounds__(256) void phaseA_kernel(
    const u16* __restrict__ kf, const u16* __restrict__ qf, const float2* __restrict__ gb2,
    u16* __restrict__ KTg, u16* __restrict__ Bg, u16* __restrict__ Mg,
    float2* __restrict__ gpk) {
  __shared__ uint8_t sm[51456];
  float* Nl  = (float*)sm;               // 64*66*4 = 16896
  float* gl  = (float*)(sm + 16896);     // 256
  float* bl  = (float*)(sm + 17152);     // 256
  float* GL  = (float*)(sm + 17408);     // 256
  u16*  Klds = (u16*)(sm + 17664);       // 64*264*2 = 33792
  float* Ml  = (float*)(sm + 17664);     // alias Klds (used after KT writeout)

  const int tid = threadIdx.x;
  const int lane = tid & 63;
  const int wv = tid >> 6;
  const int quad = lane >> 4;
  const int l16 = lane & 15;
  const int bh = blockIdx.x >> 5;        // 0..15
  const int ch = blockIdx.x & 31;        // 0..31
  const int b = bh >> 2, h = bh & 3;
  const int gr0 = b * 2048 + ch * 64;
  const size_t cid2 = (size_t)bh * 32 + ch;

  if (tid < 64) {
    float2 gv = gb2[(size_t)(gr0 + tid) * 4 + h];
    gl[tid] = gv.x; bl[tid] = gv.y;
  }
  __syncthreads();
  if (tid < 64) {
    float s = 0.f;
    for (int j = 0; j < 64; j++) { if (j <= tid) s += gl[j]; }
    GL[tid] = s;
  }
  {
    int r = tid >> 2, p = tid & 3;
    const u16* src = kf + (size_t)(gr0 + r) * 1024 + h * 256 + p * 64;
#pragma unroll
    for (int it = 0; it < 8; it++)
      *(uint4*)&Klds[r * 264 + p * 64 + it * 8] = *(const uint4*)(src + it * 8);
  }
  f32x4 ap[4], aq4[4];
#pragma unroll
  for (int nt = 0; nt < 4; nt++) { ap[nt] = (f32x4){0, 0, 0, 0}; aq4[nt] = (f32x4){0, 0, 0, 0}; }
  for (int ks = 0; ks < 8; ks++) {
    bfrag8 afk = *(const bfrag8*)(kf + (size_t)(gr0 + 16 * wv + l16) * 1024 + h * 256 + ks * 32 + quad * 8);
    bfrag8 afq = *(const bfrag8*)(qf + (size_t)(gr0 + 16 * wv + l16) * 1024 + h * 256 + ks * 32 + quad * 8);
#pragma unroll
    for (int nt = 0; nt < 4; nt++) {
      bfrag8 bfk = *(const bfrag8*)(kf + (size_t)(gr0 + 16 * nt + l16) * 1024 + h * 256 + ks * 32 + quad * 8);
      ap[nt]  = __builtin_amdgcn_mfma_f32_16x16x32_bf16(afk, bfk, ap[nt], 0, 0, 0);
      aq4[nt] = __builtin_amdgcn_mfma_f32_16x16x32_bf16(afq, bfk, aq4[nt], 0, 0, 0);
    }
  }
  __syncthreads();   // GL ready, Klds staged
#pragma unroll
  for (int nt = 0; nt < 4; nt++) {
#pragma unroll
    for (int r = 0; r < 4; r++) {
      int i = 16 * wv + quad * 4 + r;
      int j = 16 * nt + l16;
      float e = __expf(GL[i] - GL[j]);
      Nl[i * 66 + j] = (j < i) ? bl[i] * e * ap[nt][r] : 0.f;
      float bvv = (j <= i) ? e * aq4[nt][r] : 0.f;
      Bg[cid2 * 4096 + i * 64 + j] = f2bf(bvv);
    }
  }
  {
    float GC = GL[63];
    for (int e = 0; e < 64; e++) {
      int idx = e * 256 + tid;
      int i2 = idx & 63, k2 = idx >> 6;
      float kv = bf2f(Klds[i2 * 264 + k2]) * __expf(GC - GL[i2]);   // fold gout into KT
      KTg[cid2 * 16384 + (size_t)k2 * 64 + i2] = f2bf(kv);
    }
  }
  if (tid < 64) {
    float2 gp;
    gp.x = __expf(GL[tid]);
    gp.y = __expf(GL[63] - GL[tid]);
    gpk[cid2 * 64 + tid] = gp;
  }
  __syncthreads();   // N complete; KT writeout done (Ml aliases Klds)
  if (tid < 64) {
    int c = tid;
    for (int i = 0; i < 64; i++) {
      float acc = (i == c) ? bl[i] : 0.f;
      for (int j = 0; j < i; j++) acc -= Nl[i * 66 + j] * Ml[j * 66 + c];
      Ml[i * 66 + c] = acc;
    }
  }
  __syncthreads();
  for (int e = 0; e < 16; e++) {
    int idx = e * 256 + tid;
    int i2 = idx >> 6, j2 = idx & 63;
    Mg[cid2 * 4096 + i2 * 64 + j2] = f2bf(Ml[i2 * 66 + j2]);
  }
}

// -------- Phase B operand set for one chunk (all in VGPRs, prefetched) --------
struct OpsB {
  bfrag8 kf8[8], qf8[8], kt8[8], m2[2], b2f[2];
  u16 vv[8];
  float gin[4], gC;
};

DEV void loadOpsB(OpsB& o, const u16* kfc, const u16* qfc, const u16* vfc,
                  const u16* KTc, const u16* Mc, const u16* Bc,
                  const float2* gpc, int wv, int l16, int quad, int i0) {
#pragma unroll
  for (int ks = 0; ks < 8; ks++) {
    o.kf8[ks] = *(const bfrag8*)(kfc + (size_t)(16 * wv + l16) * 1024 + ks * 32 + quad * 8);
    o.qf8[ks] = *(const bfrag8*)(qfc + (size_t)(16 * wv + l16) * 1024 + ks * 32 + quad * 8);
  }
#pragma unroll
  for (int kt = 0; kt < 4; kt++)
#pragma unroll
    for (int ks = 0; ks < 2; ks++)
      o.kt8[kt * 2 + ks] = *(const bfrag8*)(KTc + (size_t)(64 * wv + kt * 16 + l16) * 64 + ks * 32 + quad * 8);
#pragma unroll
  for (int ks = 0; ks < 2; ks++) {
    o.m2[ks]  = *(const bfrag8*)(Mc + (size_t)(16 * wv + l16) * 64 + ks * 32 + quad * 8);
    o.b2f[ks] = *(const bfrag8*)(Bc + (size_t)(16 * wv + l16) * 64 + ks * 32 + quad * 8);
  }
#pragma unroll
  for (int nt = 0; nt < 2; nt++)
#pragma unroll
    for (int r = 0; r < 4; r++)
      o.vv[nt * 4 + r] = vfc[(size_t)(i0 + r) * 2048 + nt * 16 + l16];
#pragma unroll
  for (int r = 0; r < 4; r++) o.gin[r] = gpc[i0 + r].x;
  o.gC = gpc[63].x;
}

// -------- Phase B: per (b,h,v-slice32) block; sequential over 32 chunks --------
// 3 barriers/chunk; all global operands register-prefetched one chunk ahead.
__global__ __launch_bounds__(256) void phaseB_kernel(
    const u16* __restrict__ kf, const u16* __restrict__ qf, const u16* __restrict__ vf,
    const u16* __restrict__ KTg, const u16* __restrict__ Bg, const u16* __restrict__ Mg,
    const float2* __restrict__ gpk, u16* __restrict__ obuf) {
  __shared__ u16 S0T[32 * 264];   // S0^T [n][k], padded
  __shared__ u16 rhsT[32 * 72];
  __shared__ u16 dT[32 * 72];

  const int tid = threadIdx.x;
  const int lane = tid & 63;
  const int wv = tid >> 6;
  const int quad = lane >> 4;
  const int l16 = lane & 15;
  const int bh = blockIdx.x >> 4;   // 0..15
  const int sl = blockIdx.x & 15;   // v-slice of 32
  const int b = bh >> 2, h = bh & 3;
  const int i0 = quad * 4;          // row offset within wave's 16-row band

  f32x4 S[8];                       // [kt 0..3][nt 0..1]; wave wv owns k in [64*wv, 64*wv+64)
#pragma unroll
  for (int t = 0; t < 8; t++) S[t] = (f32x4){0, 0, 0, 0};

  const size_t cidb = (size_t)bh * 32;
  const u16* kfb = kf + ((size_t)b * 2048) * 1024 + h * 256;
  const u16* qfb = qf + ((size_t)b * 2048) * 1024 + h * 256;
  const u16* vfb = vf + ((size_t)b * 2048) * 2048 + h * 512 + sl * 32;
  u16* ob = obuf + ((size_t)b * 2048) * 2048 + h * 512 + sl * 32;

  OpsB cur, nxt;
  loadOpsB(cur, kfb, qfb, vfb, KTg + cidb * 16384, Mg + cidb * 4096, Bg + cidb * 4096,
           gpk + cidb * 64, wv, l16, quad, 16 * wv + i0);

  for (int ch = 0; ch < 32; ch++) {
    if (ch < 31) {
      int c1 = ch + 1;
      loadOpsB(nxt, kfb + (size_t)c1 * 64 * 1024, qfb + (size_t)c1 * 64 * 1024,
               vfb + (size_t)c1 * 64 * 2048, KTg + (cidb + c1) * 16384,
               Mg + (cidb + c1) * 4096, Bg + (cidb + c1) * 4096,
               gpk + (cidb + c1) * 64, wv, l16, quad, 16 * wv + i0);
    }
    u16* oc = ob + (size_t)ch * 64 * 2048;

    // step 1: stage S0^T (bf16)
#pragma unroll
    for (int kt = 0; kt < 4; kt++)
#pragma unroll
      for (int nt = 0; nt < 2; nt++) {
        int k = wv * 64 + kt * 16 + i0;
        f32x4 sv = S[kt * 2 + nt];
        uint2 pk;
        pk.x = pack2(sv[0], sv[1]);
        pk.y = pack2(sv[2], sv[3]);
        *(uint2*)&S0T[(nt * 16 + l16) * 264 + k] = pk;
      }
    __syncthreads();   // (a)

    // step 2: K@S0 (critical) and Q@S0 (used in step 4)
    f32x4 ar[2] = {(f32x4){0, 0, 0, 0}, (f32x4){0, 0, 0, 0}};
    f32x4 aq[2] = {(f32x4){0, 0, 0, 0}, (f32x4){0, 0, 0, 0}};
#pragma unroll
    for (int ks = 0; ks < 8; ks++) {
      bfrag8 b0 = *(const bfrag8*)&S0T[(0 * 16 + l16) * 264 + ks * 32 + quad * 8];
      bfrag8 b1 = *(const bfrag8*)&S0T[(1 * 16 + l16) * 264 + ks * 32 + quad * 8];
      ar[0] = __builtin_amdgcn_mfma_f32_16x16x32_bf16(cur.kf8[ks], b0, ar[0], 0, 0, 0);
      ar[1] = __builtin_amdgcn_mfma_f32_16x16x32_bf16(cur.kf8[ks], b1, ar[1], 0, 0, 0);
      aq[0] = __builtin_amdgcn_mfma_f32_16x16x32_bf16(cur.qf8[ks], b0, aq[0], 0, 0, 0);
      aq[1] = __builtin_amdgcn_mfma_f32_16x16x32_bf16(cur.qf8[ks], b1, aq[1], 0, 0, 0);
    }
#pragma unroll
    for (int nt = 0; nt < 2; nt++) {
      float rv[4];
#pragma unroll
      for (int r = 0; r < 4; r++)
        rv[r] = bf2f(cur.vv[nt * 4 + r]) - cur.gin[r] * ar[nt][r];
      uint2 pk;
      pk.x = pack2(rv[0], rv[1]);
      pk.y = pack2(rv[2], rv[3]);
      *(uint2*)&rhsT[(nt * 16 + l16) * 72 + 16 * wv + i0] = pk;
    }
    __syncthreads();   // (b)

    // step 3: delta = M @ rhs -> dT
    f32x4 ad[2] = {(f32x4){0, 0, 0, 0}, (f32x4){0, 0, 0, 0}};
#pragma unroll
    for (int ks = 0; ks < 2; ks++) {
#pragma unroll
      for (int nt = 0; nt < 2; nt++) {
        bfrag8 bf = *(const bfrag8*)&rhsT[(nt * 16 + l16) * 72 + ks * 32 + quad * 8];
        ad[nt] = __builtin_amdgcn_mfma_f32_16x16x32_bf16(cur.m2[ks], bf, ad[nt], 0, 0, 0);
      }
    }
#pragma unroll
    for (int nt = 0; nt < 2; nt++) {
      uint2 pk;
      pk.x = pack2(ad[nt][0], ad[nt][1]);
      pk.y = pack2(ad[nt][2], ad[nt][3]);
      *(uint2*)&dT[(nt * 16 + l16) * 72 + 16 * wv + i0] = pk;
    }
    __syncthreads();   // (c)

    // step 4: O = rowscale(gin)*(Q@S0) + B@delta
    f32x4 ao[2] = {(f32x4){0, 0, 0, 0}, (f32x4){0, 0, 0, 0}};
#pragma unroll
    for (int ks = 0; ks < 2; ks++) {
#pragma unroll
      for (int nt = 0; nt < 2; nt++) {
        bfrag8 bf = *(const bfrag8*)&dT[(nt * 16 + l16) * 72 + ks * 32 + quad * 8];
        ao[nt] = __builtin_amdgcn_mfma_f32_16x16x32_bf16(cur.b2f[ks], bf, ao[nt], 0, 0, 0);
      }
    }
#pragma unroll
    for (int nt = 0; nt < 2; nt++)
#pragma unroll
      for (int r = 0; r < 4; r++) {
        int i = 16 * wv + i0 + r;
        float ov = cur.gin[r] * aq[nt][r] + ao[nt][r];
        oc[(size_t)i * 2048 + nt * 16 + l16] = f2bf(ov);
      }

    // step 5: S = gammaC*S + KTs @ delta (KTs pre-scaled by gout in phaseA)
#pragma unroll
    for (int kt = 0; kt < 4; kt++)
#pragma unroll
      for (int nt = 0; nt < 2; nt++) {
        f32x4 c0 = S[kt * 2 + nt] * cur.gC;
#pragma unroll
        for (int ks = 0; ks < 2; ks++) {
          bfrag8 bf = *(const bfrag8*)&dT[(nt * 16 + l16) * 72 + ks * 32 + quad * 8];
          c0 = __builtin_amdgcn_mfma_f32_16x16x32_bf16(cur.kt8[kt * 2 + ks], bf, c0, 0, 0, 0);
        }
        S[kt * 2 + nt] = c0;
      }
    cur = nxt;   // no trailing barrier needed: every buffer's next write is barrier-separated from its reads
  }
}

// -------------------- gated RMS-norm of o: bf16 out --------------------
__global__ __launch_bounds__(256) void onorm_kernel(
    const u16* __restrict__ o, const u16* __restrict__ gate,
    const float* __restrict__ onw, u16* __restrict__ ofin) {
  __shared__ float sred[4];
  int row = blockIdx.x, hh = blockIdx.y, tid = threadIdx.x;
  size_t base = (size_t)row * 2048 + hh * 512;
  uint32_t oraw = *(const uint32_t*)(o + base + tid * 2);
  float o0 = bf2f(oraw & 0xffffu), o1 = bf2f(oraw >> 16);
  float ssq = blk_sum(o0 * o0 + o1 * o1, sred, tid);
  float rinv = rsqrtf(ssq * (1.f / 512.f) + 1e-6f);
  uint32_t graw = *(const uint32_t*)(gate + base + tid * 2);
  float g0 = bf2f(graw & 0xffffu), g1 = bf2f(graw >> 16);
  float r0 = o0 * rinv * onw[tid * 2 + 0] * (g0 * sigmoidf_(g0));
  float r1 = o1 * rinv * onw[tid * 2 + 1] * (g1 * sigmoidf_(g1));
  *(uint32_t*)(ofin + base + tid * 2) = pack2(r0, r1);
}

// -------------------- LN2 --------------------
__global__ __launch_bounds__(256) void ln2_kernel(
    const float* __restrict__ x1, const float* __restrict__ g2, const float* __restrict__ b2,
    u16* __restrict__ h2) {
  __shared__ float sred[4];
  int row = blockIdx.x, tid = threadIdx.x;
  const float4 xv = ((const float4*)(x1 + (size_t)row * 1024))[tid];
  float ts  = blk_sum(xv.x + xv.y + xv.z + xv.w, sred, tid);
  float ts2 = blk_sum(xv.x * xv.x + xv.y * xv.y + xv.z * xv.z + xv.w * xv.w, sred, tid);
  float mean = ts * (1.f / 1024.f);
  float inv = rsqrtf(ts2 * (1.f / 1024.f) - mean * mean + 1e-5f);
  int c = tid * 4;
  float h0 = (xv.x - mean) * inv * g2[c + 0] + b2[c + 0];
  float h1 = (xv.y - mean) * inv * g2[c + 1] + b2[c + 1];
  float h2v = (xv.z - mean) * inv * g2[c + 2] + b2[c + 2];
  float h3 = (xv.w - mean) * inv * g2[c + 3] + b2[c + 3];
  uint2 pk;
  pk.x = pack2(h0, h1);
  pk.y = pack2(h2v, h3);
  *(uint2*)(h2 + (size_t)row * 1024 + c) = pk;
}

// ==================== launch ====================
extern "C" void kernel_launch(void* const* d_in, const int* in_sizes, int n_in,
                              void* d_out, int out_size, void* d_ws, size_t ws_size,
                              hipStream_t stream) {
  (void)in_sizes; (void)n_in; (void)out_size; (void)ws_size;
  const float* x    = (const float*)d_in[0];
  const float* ln1g = (const float*)d_in[1];
  const float* ln1b = (const float*)d_in[2];
  const float* ln2g = (const float*)d_in[3];
  const float* ln2b = (const float*)d_in[4];
  const float* rmsw = (const float*)d_in[5];
  const float* Wq   = (const float*)d_in[6];
  const float* Wk   = (const float*)d_in[7];
  const float* Wv   = (const float*)d_in[8];
  const float* cwq  = (const float*)d_in[9];
  const float* cwk  = (const float*)d_in[10];
  const float* cwv  = (const float*)d_in[11];
  const float* Wa   = (const float*)d_in[12];
  const float* dtb  = (const float*)d_in[13];
  const float* Alog = (const float*)d_in[14];
  const float* Wb   = (const float*)d_in[15];
  const float* Wg   = (const float*)d_in[16];
  const float* onw  = (const float*)d_in[17];
  const float* Wo   = (const float*)d_in[18];
  const float* W2   = (const float*)d_in[19];
  const float* b2   = (const float*)d_in[20];

  uint8_t* ws = (uint8_t*)d_ws;
  const size_t MB = 1024ull * 1024;
  u16*   qkvp  = (u16*)(ws);               // 64MB
  u16*   obuf  = (u16*)(ws);               // 32MB (overlay)
  u16*   KTg   = (u16*)(ws + 32 * MB);     // 16MB  (PhaseA out, dead before gate write)
  u16*   Bg    = (u16*)(ws + 48 * MB);     // 4MB
  u16*   Mg    = (u16*)(ws + 52 * MB);     // 4MB
  float2* gpk  = (float2*)(ws + 56 * MB);  // 256KB
  u16*   gate  = (u16*)(ws + 32 * MB);     // 32MB (overlay, written after PhaseB)
  u16*   hbf   = (u16*)(ws + 64 * MB);     // 16MB
  u16*   WTqkv = (u16*)(ws + 80 * MB);     // 8MB
  u16*   WgT   = (u16*)(ws + 88 * MB);     // 4MB
  u16*   WoT   = (u16*)(ws + 92 * MB);     // 4MB
  u16*   W2T   = (u16*)(ws + 96 * MB);     // 2MB
  u16*   qf    = (u16*)(ws + 98 * MB);     // 16MB
  u16*   kf    = (u16*)(ws + 114 * MB);    // 16MB
  u16*   vf    = (u16*)(ws + 130 * MB);    // 32MB
  u16*   ofin  = (u16*)(ws + 98 * MB);     // 32MB (overlay qf/kf)
  u16*   h2bf  = (u16*)(ws + 130 * MB);    // 16MB (overlay vf)
  float2* gb2  = (float2*)(ws + 162 * MB); // 256KB
  float* x1    = (float*)d_out;
  float* outp  = (float*)d_out;

  dim3 tb(32, 8);
  transpose_w<<<dim3(32, 32), tb, 0, stream>>>(Wq, WTqkv,               1024, 1024);
  transpose_w<<<dim3(32, 32), tb, 0, stream>>>(Wk, WTqkv + 1024 * 1024, 1024, 1024);
  transpose_w<<<dim3(64, 32), tb, 0, stream>>>(Wv, WTqkv + 2048 * 1024, 1024, 2048);
  transpose_w<<<dim3(64, 32), tb, 0, stream>>>(Wg, WgT,                 1024, 2048);
  transpose_w<<<dim3(32, 64), tb, 0, stream>>>(Wo, WoT,                 2048, 1024);
  transpose_w<<<dim3(32, 32), tb, 0, stream>>>(W2, W2T,                 1024, 1024);

  k1_kernel<<<8192, 256, 0, stream>>>(x, ln1g, ln1b, rmsw, Wa, Wb, dtb, Alog, hbf, gb2);
  gemm_bt<0><<<dim3(32, 64), 256, 0, stream>>>(hbf, WTqkv, 8192, 4096, 1024, nullptr, qkvp, nullptr, nullptr);
  conv_qk_kernel<<<dim3(8192, 8), 256, 0, stream>>>(qkvp, cwq, cwk, qf, kf);
  conv_v_kernel<<<dim3(8192, 2), 256, 0, stream>>>(qkvp, cwv, vf);
  phaseA_kernel<<<512, 256, 0, stream>>>(kf, qf, gb2, KTg, Bg, Mg, gpk);
  phaseB_kernel<<<256, 256, 0, stream>>>(kf, qf, vf, KTg, Bg, Mg, gpk, obuf);
  gemm_bt<0><<<dim3(16, 64), 256, 0, stream>>>(hbf, WgT, 8192, 2048, 1024, nullptr, gate, nullptr, nullptr);
  onorm_kernel<<<dim3(8192, 4), 256, 0, stream>>>(obuf, gate, onw, ofin);
  gemm_bt<1><<<dim3(8, 64), 256, 0, stream>>>(ofin, WoT, 8192, 1024, 2048, x1, nullptr, x, nullptr);
  ln2_kernel<<<8192, 256, 0, stream>>>(x1, ln2g, ln2b, h2bf);
  gemm_bt<2><<<dim3(8, 64), 256, 0, stream>>>(h2bf, W2T, 8192, 1024, 1024, outp, nullptr, x1, b2);
}